// Round 3
// baseline (326.680 us; speedup 1.0000x reference)
//
#include <hip/hip_runtime.h>
#include <hip/hip_bf16.h>

#define C_DIM 128
#define SCALE 0.17677669529663687f

typedef __attribute__((ext_vector_type(8))) short frag8;
typedef __attribute__((ext_vector_type(4))) float f32x4;
typedef __attribute__((ext_vector_type(4))) unsigned int u32x4;

// ---- LDS (ushort units), 17216 total = 34432 B -> 4 blocks/CU ----
//  [0,8000)      K block: head h at h*2000, rows 50 x Q_STR=40 (row 49 trash)
//  [8000,17216)  Vt block: head h at 8000+h*2304, rows 32 x VT_STR=72
//                (token cols 49..63 garbage, cancelled by P zeros)
//  x staging rows 0..48 stride 136 = [0,6664) overlays K block (dead after
//  barrier 2); act rows 0..49 stride 136 = [0,6800) overlays K block (safe
//  after barrier 3 = all kf reads retired).
// Q and P live ONLY in registers: the C-layout -> A/B-frag conversion is a
// cross-q-group shuffle (srcA=((q&1)<<5)+n16, srcB=srcA+16, tile sel = q>>1).
// Pad tokens: reads clamp row to 48; writes go to trash row 49; softmax guards
// j<49 (garbage keys, incl. cross-head race garbage, only feed masked cols).
#define XACT_STR 136
#define VT_BASE 8000
#define VT_PER_HEAD 2304
#define Q_STR 40
#define VT_STR 72
#define SMEM_TOT 17216

__device__ __forceinline__ unsigned short f2b(float x) {
    __hip_bfloat16 h = __float2bfloat16(x);
    return __builtin_bit_cast(unsigned short, h);
}
__device__ __forceinline__ unsigned pk2(float a, float b) {
    return ((unsigned)f2b(b) << 16) | (unsigned)f2b(a);
}
__device__ __forceinline__ void add4(f32x4& a, float4 m) {
    a[0] += m.x; a[1] += m.y; a[2] += m.z; a[3] += m.w;
}

// fp32 weights -> bf16 ws: [0,49152) qkv_w, [49152,65536) proj_w
__global__ void convert_weights(const float4* __restrict__ qkvw,
                                const float4* __restrict__ projw,
                                ushort4* __restrict__ wbf) {
    int i = blockIdx.x * 256 + threadIdx.x;
    float4 v = (i < 12288) ? qkvw[i] : projw[i - 12288];
    ushort4 p;
    p.x = f2b(v.x); p.y = f2b(v.y); p.z = f2b(v.z); p.w = f2b(v.w);
    wbf[i] = p;
}

// mask[64][49][49] fp32 -> pm[64][49][64] fp32 (cols 49..63 = 0).
__global__ void pad_mask(const float* __restrict__ mask, float* __restrict__ pm) {
    int t = blockIdx.x * 256 + threadIdx.x;      // 196*256 = 50176 exactly
    int w = t / 784, rem = t % 784, i = rem >> 4, tq = rem & 15;
    const float* src = mask + (size_t)w * 2401 + i * 49;
    int j = tq * 4;
    float4 v;
    v.x = (j     < 49) ? src[j]     : 0.f;
    v.y = (j + 1 < 49) ? src[j + 1] : 0.f;
    v.z = (j + 2 < 49) ? src[j + 2] : 0.f;
    v.w = (j + 3 < 49) ? src[j + 3] : 0.f;
    ((float4*)pm)[t] = v;
}

__global__ __launch_bounds__(256, 4) void attn_mfma(
    const float* __restrict__ x,
    const float* __restrict__ pmask,
    const float* __restrict__ qkv_b,
    const float* __restrict__ proj_b,
    const unsigned short* __restrict__ wq,
    float* __restrict__ out)
{
    __shared__ __align__(16) unsigned short sm[SMEM_TOT];

    const int b = blockIdx.x, tid = threadIdx.x;
    const int h    = tid >> 6;   // wave = head, owns the full chain
    const int lane = tid & 63;
    const int n16  = lane & 15;
    const int q    = lane >> 4;

    // ---- stage x[b] rows 0..48 -> bf16 (base 0, stride 136) ----
    {
        const float4* xg = (const float4*)(x + (size_t)b * 6272);
        for (int i = tid; i < 1568; i += 256) {
            float4 v = xg[i];
            int row = i >> 5, col = (i & 31) << 2;
            uint2 pk; pk.x = pk2(v.x, v.y); pk.y = pk2(v.z, v.w);
            *(uint2*)&sm[row * XACT_STR + col] = pk;
        }
    }
    __syncthreads();  // (1) x staged

    // ---- x frags, pad rows clamp to row 48 ----
    frag8 xf[4][4];
#pragma unroll
    for (int tt = 0; tt < 4; ++tt)
#pragma unroll
        for (int ks = 0; ks < 4; ++ks)
            xf[tt][ks] = *(const frag8*)&sm[min(tt * 16 + n16, 48) * XACT_STR + ks * 32 + q * 8];
    __syncthreads();  // (2) x in regs everywhere -> K/Vt writes may overlay staging

    const int KB = h * 2000;
    const int VB = VT_BASE + h * VT_PER_HEAD;

    // ---- Phase A: K first (max LDS write->read gap), then V, then Q ----
    // K: D = W x^T -> K[tok][ch] in LDS
#pragma unroll
    for (int ct = 0; ct < 2; ++ct) {
        const unsigned short* wrow = wq + (size_t)(C_DIM + h * 32 + ct * 16 + n16) * C_DIM;
        frag8 wf[4];
#pragma unroll
        for (int ks = 0; ks < 4; ++ks) wf[ks] = *(const frag8*)(wrow + ks * 32 + q * 8);
        float4 b4 = *(const float4*)(qkv_b + C_DIM + h * 32 + ct * 16 + q * 4);
#pragma unroll
        for (int tt = 0; tt < 4; ++tt) {
            f32x4 acc = {0.f, 0.f, 0.f, 0.f};
#pragma unroll
            for (int ks = 0; ks < 4; ++ks)
                acc = __builtin_amdgcn_mfma_f32_16x16x32_bf16(wf[ks], xf[tt][ks], acc, 0, 0, 0);
            uint2 pk;
            pk.x = pk2(acc[0] + b4.x, acc[1] + b4.y);
            pk.y = pk2(acc[2] + b4.z, acc[3] + b4.w);
            *(uint2*)&sm[KB + min(tt * 16 + n16, 49) * Q_STR + ct * 16 + q * 4] = pk;
        }
    }
    // V: D = x W^T -> Vt[ch][tok] in LDS
#pragma unroll
    for (int ct = 0; ct < 2; ++ct) {
        const unsigned short* wrow = wq + (size_t)(2 * C_DIM + h * 32 + ct * 16 + n16) * C_DIM;
        frag8 wf[4];
#pragma unroll
        for (int ks = 0; ks < 4; ++ks) wf[ks] = *(const frag8*)(wrow + ks * 32 + q * 8);
        float bias = qkv_b[2 * C_DIM + h * 32 + ct * 16 + n16];
#pragma unroll
        for (int tt = 0; tt < 4; ++tt) {
            f32x4 acc = {0.f, 0.f, 0.f, 0.f};
#pragma unroll
            for (int ks = 0; ks < 4; ++ks)
                acc = __builtin_amdgcn_mfma_f32_16x16x32_bf16(xf[tt][ks], wf[ks], acc, 0, 0, 0);
            uint2 pk;
            pk.x = pk2(acc[0] + bias, acc[1] + bias);
            pk.y = pk2(acc[2] + bias, acc[3] + bias);
            *(uint2*)&sm[VB + (ct * 16 + n16) * VT_STR + tt * 16 + q * 4] = pk;
        }
    }
    // Q: D = W x^T kept as packed bf16 words in regs (qw[tt][ct][w]),
    // word w = ch pair (ct*16+q*4+2w, +2w+1) for tok tt*16+n16.
    unsigned qw[4][2][2];
#pragma unroll
    for (int ct = 0; ct < 2; ++ct) {
        const unsigned short* wrow = wq + (size_t)(h * 32 + ct * 16 + n16) * C_DIM;
        frag8 wf[4];
#pragma unroll
        for (int ks = 0; ks < 4; ++ks) wf[ks] = *(const frag8*)(wrow + ks * 32 + q * 8);
        float4 b4 = *(const float4*)(qkv_b + h * 32 + ct * 16 + q * 4);
#pragma unroll
        for (int tt = 0; tt < 4; ++tt) {
            f32x4 acc = {0.f, 0.f, 0.f, 0.f};
#pragma unroll
            for (int ks = 0; ks < 4; ++ks)
                acc = __builtin_amdgcn_mfma_f32_16x16x32_bf16(wf[ks], xf[tt][ks], acc, 0, 0, 0);
            qw[tt][ct][0] = pk2((acc[0] + b4.x) * SCALE, (acc[1] + b4.y) * SCALE);
            qw[tt][ct][1] = pk2((acc[2] + b4.z) * SCALE, (acc[3] + b4.w) * SCALE);
        }
    }

    // ---- qf via register shuffles (no LDS round trip) ----
    // qf[it] elem e = Q[tok=it*16+n16][ch=q*8+e]: src lane ((q&1)<<5)+n16
    // (+16 for e>=4), word e>>1&1... word = (e&3)>>1, ct sel = q>>1.
    const int srcA = ((q & 1) << 5) + n16;
    const int srcB = srcA + 16;
    const int hi = q >> 1;
    frag8 qf[4];
#pragma unroll
    for (int it = 0; it < 4; ++it) {
        unsigned a00 = __shfl((int)qw[it][0][0], srcA);
        unsigned a10 = __shfl((int)qw[it][1][0], srcA);
        unsigned a01 = __shfl((int)qw[it][0][1], srcA);
        unsigned a11 = __shfl((int)qw[it][1][1], srcA);
        unsigned b00 = __shfl((int)qw[it][0][0], srcB);
        unsigned b10 = __shfl((int)qw[it][1][0], srcB);
        unsigned b01 = __shfl((int)qw[it][0][1], srcB);
        unsigned b11 = __shfl((int)qw[it][1][1], srcB);
        u32x4 t;
        t[0] = hi ? a10 : a00;
        t[1] = hi ? a11 : a01;
        t[2] = hi ? b10 : b00;
        t[3] = hi ? b11 : b01;
        qf[it] = __builtin_bit_cast(frag8, t);
    }

    // ---- kf/vf loads (kf rows 49..63 garbage -> masked cols; race-safe) ----
    frag8 kf[4];
#pragma unroll
    for (int t = 0; t < 4; ++t)
        kf[t] = *(const frag8*)&sm[KB + (t * 16 + n16) * Q_STR + q * 8];
    frag8 vf[2][2];
#pragma unroll
    for (int ct = 0; ct < 2; ++ct)
#pragma unroll
        for (int ks = 0; ks < 2; ++ks)
            vf[ct][ks] = *(const frag8*)&sm[VB + (ct * 16 + n16) * VT_STR + ks * 32 + q * 8];
    __syncthreads();  // (3) all kf reads retired -> act may overlay K block

    // ---- fused S -> softmax -> PV per 16-query tile ----
    const float4* pm4 = (const float4*)(pmask + (size_t)(b & 63) * 3136);
    f32x4 o[2][4];
#pragma unroll
    for (int ct = 0; ct < 2; ++ct)
#pragma unroll
        for (int nt = 0; nt < 4; ++nt) o[ct][nt] = (f32x4){0.f, 0.f, 0.f, 0.f};

#pragma unroll
    for (int it = 0; it < 4; ++it) {
        int ii = min(it * 16 + n16, 48);
        float4 mj[4];
#pragma unroll
        for (int jt = 0; jt < 4; ++jt) mj[jt] = pm4[ii * 16 + q + jt * 4];

        f32x4 s4[4];
#pragma unroll
        for (int jt = 0; jt < 4; ++jt) {
            s4[jt] = (f32x4){0.f, 0.f, 0.f, 0.f};
            s4[jt] = __builtin_amdgcn_mfma_f32_16x16x32_bf16(kf[jt], qf[it], s4[jt], 0, 0, 0);
        }
#pragma unroll
        for (int jt = 0; jt < 4; ++jt) add4(s4[jt], mj[jt]);

        float mx = -1e30f;
#pragma unroll
        for (int jt = 0; jt < 4; ++jt)
#pragma unroll
            for (int r = 0; r < 4; ++r)
                if (jt * 16 + q * 4 + r < 49) mx = fmaxf(mx, s4[jt][r]);
        mx = fmaxf(mx, __shfl_xor(mx, 16));
        mx = fmaxf(mx, __shfl_xor(mx, 32));

        float sum = 0.f;
#pragma unroll
        for (int jt = 0; jt < 4; ++jt)
#pragma unroll
            for (int r = 0; r < 4; ++r) {
                float e = (jt * 16 + q * 4 + r < 49) ? __expf(s4[jt][r] - mx) : 0.f;
                s4[jt][r] = e;
                sum += e;
            }
        sum += __shfl_xor(sum, 16);
        sum += __shfl_xor(sum, 32);
        float inv = __builtin_amdgcn_rcpf(sum);

        // pack unnormalized P (e in (0,1], bf16-safe); normalize o afterwards
        unsigned pw[4][2];
#pragma unroll
        for (int jt = 0; jt < 4; ++jt) {
            pw[jt][0] = pk2(s4[jt][0], s4[jt][1]);
            pw[jt][1] = pk2(s4[jt][2], s4[jt][3]);
        }
        // pf[ks] elem e = P[key=ks*32+q*8+e][tok=it*16+n16]: jt sel = 2ks+hi
#pragma unroll
        for (int ks = 0; ks < 2; ++ks) {
            unsigned a0  = __shfl((int)pw[2 * ks][0],     srcA);
            unsigned a0h = __shfl((int)pw[2 * ks + 1][0], srcA);
            unsigned a1  = __shfl((int)pw[2 * ks][1],     srcA);
            unsigned a1h = __shfl((int)pw[2 * ks + 1][1], srcA);
            unsigned b0  = __shfl((int)pw[2 * ks][0],     srcB);
            unsigned b0h = __shfl((int)pw[2 * ks + 1][0], srcB);
            unsigned b1  = __shfl((int)pw[2 * ks][1],     srcB);
            unsigned b1h = __shfl((int)pw[2 * ks + 1][1], srcB);
            u32x4 t;
            t[0] = hi ? a0h : a0;
            t[1] = hi ? a1h : a1;
            t[2] = hi ? b0h : b0;
            t[3] = hi ? b1h : b1;
            frag8 pf = __builtin_bit_cast(frag8, t);
#pragma unroll
            for (int ct = 0; ct < 2; ++ct)
                o[ct][it] = __builtin_amdgcn_mfma_f32_16x16x32_bf16(vf[ct][ks], pf, o[ct][it], 0, 0, 0);
        }
#pragma unroll
        for (int ct = 0; ct < 2; ++ct)
#pragma unroll
            for (int r = 0; r < 4; ++r) o[ct][it][r] *= inv;
    }

    // ---- act[tok][128ch] rows 0..49 stride 136 overlays K block ----
#pragma unroll
    for (int ct = 0; ct < 2; ++ct)
#pragma unroll
        for (int nt = 0; nt < 4; ++nt) {
            uint2 pk;
            pk.x = pk2(o[ct][nt][0], o[ct][nt][1]);
            pk.y = pk2(o[ct][nt][2], o[ct][nt][3]);
            *(uint2*)&sm[min(nt * 16 + n16, 49) * XACT_STR + h * 32 + ct * 16 + q * 4] = pk;
        }

    // proj weights + biases: issue under the barrier wait
    const unsigned short* pwq = wq + 49152;
    frag8 wf2[2][4];
#pragma unroll
    for (int ct = 0; ct < 2; ++ct)
#pragma unroll
        for (int ks = 0; ks < 4; ++ks)
            wf2[ct][ks] = *(const frag8*)(pwq + (size_t)(h * 32 + ct * 16 + n16) * C_DIM + ks * 32 + q * 8);
    float4 pb4[2];
#pragma unroll
    for (int ct = 0; ct < 2; ++ct)
        pb4[ct] = *(const float4*)(proj_b + h * 32 + ct * 16 + q * 4);
    __syncthreads();  // (4) act complete

    // ---- Phase D: out^T = W act^T -> float4 stores ----
    float* outb = out + (size_t)b * 6272;
    frag8 af[4][4];
#pragma unroll
    for (int nt = 0; nt < 4; ++nt)
#pragma unroll
        for (int ks = 0; ks < 4; ++ks)
            af[nt][ks] = *(const frag8*)&sm[min(nt * 16 + n16, 48) * XACT_STR + ks * 32 + q * 8];
#pragma unroll
    for (int nt = 0; nt < 4; ++nt) {
        int tok = nt * 16 + n16;
#pragma unroll
        for (int ct = 0; ct < 2; ++ct) {
            f32x4 acc = {0.f, 0.f, 0.f, 0.f};
#pragma unroll
            for (int ks = 0; ks < 4; ++ks)
                acc = __builtin_amdgcn_mfma_f32_16x16x32_bf16(wf2[ct][ks], af[nt][ks], acc, 0, 0, 0);
            if (tok < 49)
                *(float4*)&outb[tok * C_DIM + h * 32 + ct * 16 + q * 4] =
                    make_float4(acc[0] + pb4[ct].x, acc[1] + pb4[ct].y,
                                acc[2] + pb4[ct].z, acc[3] + pb4[ct].w);
        }
    }
}

extern "C" void kernel_launch(void* const* d_in, const int* in_sizes, int n_in,
                              void* d_out, int out_size, void* d_ws, size_t ws_size,
                              hipStream_t stream) {
    const float* x      = (const float*)d_in[0];
    const float* mask   = (const float*)d_in[1];
    const float* qkv_b  = (const float*)d_in[3];
    const float* proj_b = (const float*)d_in[5];

    unsigned short* wbf = (unsigned short*)d_ws;                   // 131072 B
    float* pmask = (float*)((char*)d_ws + 131072);                 // 802816 B
    convert_weights<<<64, 256, 0, stream>>>((const float4*)d_in[2],
                                            (const float4*)d_in[4],
                                            (ushort4*)wbf);
    pad_mask<<<196, 256, 0, stream>>>(mask, pmask);
    attn_mfma<<<4096, 256, 0, stream>>>(x, pmask, qkv_b, proj_b, wbf, (float*)d_out);
}

// Round 4
// 277.007 us; speedup vs baseline: 1.1793x; 1.1793x over previous
//
#include <hip/hip_runtime.h>
#include <hip/hip_bf16.h>

#define C_DIM 128
#define SCALE 0.17677669529663687f

typedef __attribute__((ext_vector_type(8))) short frag8;
typedef __attribute__((ext_vector_type(4))) float f32x4;
typedef __attribute__((ext_vector_type(4))) unsigned int u32x4;

// ---- LDS (ushort units), 17216 total = 34432 B ----
//  [0,8000)      K block: head h at h*2000, rows 50 x Q_STR=40 (row 49 trash)
//  [8000,17216)  Vt block: head h at 8000+h*2304, rows 32 x VT_STR=72
//                (token cols 49..63 garbage, cancelled by P zeros)
//  x staging rows 0..48 stride 136 = [0,6664) overlays K block (dead after
//  barrier 2); act rows 0..49 stride 136 = [0,6800) overlays K block (safe
//  after barrier 3 = all kf reads retired).
// Q and P live ONLY in registers: the C-layout -> A/B-frag conversion is a
// cross-q-group shuffle (srcA=((q&1)<<5)+n16, srcB=srcA+16, tile sel = q>>1).
// Pad tokens: reads clamp row to 48; writes go to trash row 49; softmax guards
// j<49 (garbage keys, incl. cross-head race garbage, only feed masked cols).
//
// NOTE on launch bounds: (256,4) caused a VGPR=64 allocation + massive scratch
// spill (WRITE_SIZE 3x, round 3). Peak live set is ~115-135 VGPRs, so we bound
// at 3 waves/EU (cap ~170); if the allocator lands <=128 the LDS footprint
// still permits 4 blocks/CU at runtime.
#define XACT_STR 136
#define VT_BASE 8000
#define VT_PER_HEAD 2304
#define Q_STR 40
#define VT_STR 72
#define SMEM_TOT 17216

__device__ __forceinline__ unsigned short f2b(float x) {
    __hip_bfloat16 h = __float2bfloat16(x);
    return __builtin_bit_cast(unsigned short, h);
}
__device__ __forceinline__ unsigned pk2(float a, float b) {
    return ((unsigned)f2b(b) << 16) | (unsigned)f2b(a);
}
__device__ __forceinline__ void add4(f32x4& a, float4 m) {
    a[0] += m.x; a[1] += m.y; a[2] += m.z; a[3] += m.w;
}

// fp32 weights -> bf16 ws: [0,49152) qkv_w, [49152,65536) proj_w
__global__ void convert_weights(const float4* __restrict__ qkvw,
                                const float4* __restrict__ projw,
                                ushort4* __restrict__ wbf) {
    int i = blockIdx.x * 256 + threadIdx.x;
    float4 v = (i < 12288) ? qkvw[i] : projw[i - 12288];
    ushort4 p;
    p.x = f2b(v.x); p.y = f2b(v.y); p.z = f2b(v.z); p.w = f2b(v.w);
    wbf[i] = p;
}

// mask[64][49][49] fp32 -> pm[64][49][64] fp32 (cols 49..63 = 0).
__global__ void pad_mask(const float* __restrict__ mask, float* __restrict__ pm) {
    int t = blockIdx.x * 256 + threadIdx.x;      // 196*256 = 50176 exactly
    int w = t / 784, rem = t % 784, i = rem >> 4, tq = rem & 15;
    const float* src = mask + (size_t)w * 2401 + i * 49;
    int j = tq * 4;
    float4 v;
    v.x = (j     < 49) ? src[j]     : 0.f;
    v.y = (j + 1 < 49) ? src[j + 1] : 0.f;
    v.z = (j + 2 < 49) ? src[j + 2] : 0.f;
    v.w = (j + 3 < 49) ? src[j + 3] : 0.f;
    ((float4*)pm)[t] = v;
}

__global__ __launch_bounds__(256, 3) void attn_mfma(
    const float* __restrict__ x,
    const float* __restrict__ pmask,
    const float* __restrict__ qkv_b,
    const float* __restrict__ proj_b,
    const unsigned short* __restrict__ wq,
    float* __restrict__ out)
{
    __shared__ __align__(16) unsigned short sm[SMEM_TOT];

    const int b = blockIdx.x, tid = threadIdx.x;
    const int h    = tid >> 6;   // wave = head, owns the full chain
    const int lane = tid & 63;
    const int n16  = lane & 15;
    const int q    = lane >> 4;

    // ---- stage x[b] rows 0..48 -> bf16 (base 0, stride 136) ----
    {
        const float4* xg = (const float4*)(x + (size_t)b * 6272);
        for (int i = tid; i < 1568; i += 256) {
            float4 v = xg[i];
            int row = i >> 5, col = (i & 31) << 2;
            uint2 pk; pk.x = pk2(v.x, v.y); pk.y = pk2(v.z, v.w);
            *(uint2*)&sm[row * XACT_STR + col] = pk;
        }
    }
    __syncthreads();  // (1) x staged

    // ---- x frags, pad rows clamp to row 48 ----
    frag8 xf[4][4];
#pragma unroll
    for (int tt = 0; tt < 4; ++tt)
#pragma unroll
        for (int ks = 0; ks < 4; ++ks)
            xf[tt][ks] = *(const frag8*)&sm[min(tt * 16 + n16, 48) * XACT_STR + ks * 32 + q * 8];
    __syncthreads();  // (2) x in regs everywhere -> K/Vt writes may overlay staging

    const int KB = h * 2000;
    const int VB = VT_BASE + h * VT_PER_HEAD;

    // ---- Phase A: K first (max LDS write->read gap), then V, then Q ----
    // K: D = W x^T -> K[tok][ch] in LDS
#pragma unroll
    for (int ct = 0; ct < 2; ++ct) {
        const unsigned short* wrow = wq + (size_t)(C_DIM + h * 32 + ct * 16 + n16) * C_DIM;
        frag8 wf[4];
#pragma unroll
        for (int ks = 0; ks < 4; ++ks) wf[ks] = *(const frag8*)(wrow + ks * 32 + q * 8);
        float4 b4 = *(const float4*)(qkv_b + C_DIM + h * 32 + ct * 16 + q * 4);
#pragma unroll
        for (int tt = 0; tt < 4; ++tt) {
            f32x4 acc = {0.f, 0.f, 0.f, 0.f};
#pragma unroll
            for (int ks = 0; ks < 4; ++ks)
                acc = __builtin_amdgcn_mfma_f32_16x16x32_bf16(wf[ks], xf[tt][ks], acc, 0, 0, 0);
            uint2 pk;
            pk.x = pk2(acc[0] + b4.x, acc[1] + b4.y);
            pk.y = pk2(acc[2] + b4.z, acc[3] + b4.w);
            *(uint2*)&sm[KB + min(tt * 16 + n16, 49) * Q_STR + ct * 16 + q * 4] = pk;
        }
    }
    // V: D = x W^T -> Vt[ch][tok] in LDS
#pragma unroll
    for (int ct = 0; ct < 2; ++ct) {
        const unsigned short* wrow = wq + (size_t)(2 * C_DIM + h * 32 + ct * 16 + n16) * C_DIM;
        frag8 wf[4];
#pragma unroll
        for (int ks = 0; ks < 4; ++ks) wf[ks] = *(const frag8*)(wrow + ks * 32 + q * 8);
        float bias = qkv_b[2 * C_DIM + h * 32 + ct * 16 + n16];
#pragma unroll
        for (int tt = 0; tt < 4; ++tt) {
            f32x4 acc = {0.f, 0.f, 0.f, 0.f};
#pragma unroll
            for (int ks = 0; ks < 4; ++ks)
                acc = __builtin_amdgcn_mfma_f32_16x16x32_bf16(xf[tt][ks], wf[ks], acc, 0, 0, 0);
            uint2 pk;
            pk.x = pk2(acc[0] + bias, acc[1] + bias);
            pk.y = pk2(acc[2] + bias, acc[3] + bias);
            *(uint2*)&sm[VB + (ct * 16 + n16) * VT_STR + tt * 16 + q * 4] = pk;
        }
    }
    // Q: D = W x^T kept as packed bf16 words in regs (qw[tt][ct][w]),
    // word w = ch pair (ct*16+q*4+2w, +2w+1) for tok tt*16+n16.
    unsigned qw[4][2][2];
#pragma unroll
    for (int ct = 0; ct < 2; ++ct) {
        const unsigned short* wrow = wq + (size_t)(h * 32 + ct * 16 + n16) * C_DIM;
        frag8 wf[4];
#pragma unroll
        for (int ks = 0; ks < 4; ++ks) wf[ks] = *(const frag8*)(wrow + ks * 32 + q * 8);
        float4 b4 = *(const float4*)(qkv_b + h * 32 + ct * 16 + q * 4);
#pragma unroll
        for (int tt = 0; tt < 4; ++tt) {
            f32x4 acc = {0.f, 0.f, 0.f, 0.f};
#pragma unroll
            for (int ks = 0; ks < 4; ++ks)
                acc = __builtin_amdgcn_mfma_f32_16x16x32_bf16(wf[ks], xf[tt][ks], acc, 0, 0, 0);
            qw[tt][ct][0] = pk2((acc[0] + b4.x) * SCALE, (acc[1] + b4.y) * SCALE);
            qw[tt][ct][1] = pk2((acc[2] + b4.z) * SCALE, (acc[3] + b4.w) * SCALE);
        }
    }

    // ---- qf via register shuffles (no LDS round trip) ----
    // qf[it] elem e = Q[tok=it*16+n16][ch=q*8+e]: src lane ((q&1)<<5)+n16
    // (+16 for e>=4), word = (e&3)>>1, ct sel = q>>1.
    const int srcA = ((q & 1) << 5) + n16;
    const int srcB = srcA + 16;
    const int hi = q >> 1;
    frag8 qf[4];
#pragma unroll
    for (int it = 0; it < 4; ++it) {
        unsigned a00 = __shfl((int)qw[it][0][0], srcA);
        unsigned a10 = __shfl((int)qw[it][1][0], srcA);
        unsigned a01 = __shfl((int)qw[it][0][1], srcA);
        unsigned a11 = __shfl((int)qw[it][1][1], srcA);
        unsigned b00 = __shfl((int)qw[it][0][0], srcB);
        unsigned b10 = __shfl((int)qw[it][1][0], srcB);
        unsigned b01 = __shfl((int)qw[it][0][1], srcB);
        unsigned b11 = __shfl((int)qw[it][1][1], srcB);
        u32x4 t;
        t[0] = hi ? a10 : a00;
        t[1] = hi ? a11 : a01;
        t[2] = hi ? b10 : b00;
        t[3] = hi ? b11 : b01;
        qf[it] = __builtin_bit_cast(frag8, t);
    }

    // ---- kf/vf loads (kf rows 49..63 garbage -> masked cols; race-safe) ----
    frag8 kf[4];
#pragma unroll
    for (int t = 0; t < 4; ++t)
        kf[t] = *(const frag8*)&sm[KB + (t * 16 + n16) * Q_STR + q * 8];
    frag8 vf[2][2];
#pragma unroll
    for (int ct = 0; ct < 2; ++ct)
#pragma unroll
        for (int ks = 0; ks < 2; ++ks)
            vf[ct][ks] = *(const frag8*)&sm[VB + (ct * 16 + n16) * VT_STR + ks * 32 + q * 8];
    __syncthreads();  // (3) all kf reads retired -> act may overlay K block

    // ---- fused S -> softmax -> PV per 16-query tile ----
    const float4* pm4 = (const float4*)(pmask + (size_t)(b & 63) * 3136);
    f32x4 o[2][4];
#pragma unroll
    for (int ct = 0; ct < 2; ++ct)
#pragma unroll
        for (int nt = 0; nt < 4; ++nt) o[ct][nt] = (f32x4){0.f, 0.f, 0.f, 0.f};

#pragma unroll
    for (int it = 0; it < 4; ++it) {
        int ii = min(it * 16 + n16, 48);
        float4 mj[4];
#pragma unroll
        for (int jt = 0; jt < 4; ++jt) mj[jt] = pm4[ii * 16 + q + jt * 4];

        f32x4 s4[4];
#pragma unroll
        for (int jt = 0; jt < 4; ++jt) {
            s4[jt] = (f32x4){0.f, 0.f, 0.f, 0.f};
            s4[jt] = __builtin_amdgcn_mfma_f32_16x16x32_bf16(kf[jt], qf[it], s4[jt], 0, 0, 0);
        }
#pragma unroll
        for (int jt = 0; jt < 4; ++jt) add4(s4[jt], mj[jt]);

        float mx = -1e30f;
#pragma unroll
        for (int jt = 0; jt < 4; ++jt)
#pragma unroll
            for (int r = 0; r < 4; ++r)
                if (jt * 16 + q * 4 + r < 49) mx = fmaxf(mx, s4[jt][r]);
        mx = fmaxf(mx, __shfl_xor(mx, 16));
        mx = fmaxf(mx, __shfl_xor(mx, 32));

        float sum = 0.f;
#pragma unroll
        for (int jt = 0; jt < 4; ++jt)
#pragma unroll
            for (int r = 0; r < 4; ++r) {
                float e = (jt * 16 + q * 4 + r < 49) ? __expf(s4[jt][r] - mx) : 0.f;
                s4[jt][r] = e;
                sum += e;
            }
        sum += __shfl_xor(sum, 16);
        sum += __shfl_xor(sum, 32);
        float inv = __builtin_amdgcn_rcpf(sum);

        // pack unnormalized P (e in (0,1], bf16-safe); normalize o afterwards
        unsigned pw[4][2];
#pragma unroll
        for (int jt = 0; jt < 4; ++jt) {
            pw[jt][0] = pk2(s4[jt][0], s4[jt][1]);
            pw[jt][1] = pk2(s4[jt][2], s4[jt][3]);
        }
        // pf[ks] elem e = P[key=ks*32+q*8+e][tok=it*16+n16]: jt sel = 2ks+hi
#pragma unroll
        for (int ks = 0; ks < 2; ++ks) {
            unsigned a0  = __shfl((int)pw[2 * ks][0],     srcA);
            unsigned a0h = __shfl((int)pw[2 * ks + 1][0], srcA);
            unsigned a1  = __shfl((int)pw[2 * ks][1],     srcA);
            unsigned a1h = __shfl((int)pw[2 * ks + 1][1], srcA);
            unsigned b0  = __shfl((int)pw[2 * ks][0],     srcB);
            unsigned b0h = __shfl((int)pw[2 * ks + 1][0], srcB);
            unsigned b1  = __shfl((int)pw[2 * ks][1],     srcB);
            unsigned b1h = __shfl((int)pw[2 * ks + 1][1], srcB);
            u32x4 t;
            t[0] = hi ? a0h : a0;
            t[1] = hi ? a1h : a1;
            t[2] = hi ? b0h : b0;
            t[3] = hi ? b1h : b1;
            frag8 pf = __builtin_bit_cast(frag8, t);
#pragma unroll
            for (int ct = 0; ct < 2; ++ct)
                o[ct][it] = __builtin_amdgcn_mfma_f32_16x16x32_bf16(vf[ct][ks], pf, o[ct][it], 0, 0, 0);
        }
#pragma unroll
        for (int ct = 0; ct < 2; ++ct)
#pragma unroll
            for (int r = 0; r < 4; ++r) o[ct][it][r] *= inv;
    }

    // ---- act[tok][128ch] rows 0..49 stride 136 overlays K block ----
#pragma unroll
    for (int ct = 0; ct < 2; ++ct)
#pragma unroll
        for (int nt = 0; nt < 4; ++nt) {
            uint2 pk;
            pk.x = pk2(o[ct][nt][0], o[ct][nt][1]);
            pk.y = pk2(o[ct][nt][2], o[ct][nt][3]);
            *(uint2*)&sm[min(nt * 16 + n16, 49) * XACT_STR + h * 32 + ct * 16 + q * 4] = pk;
        }

    // proj weights + biases: issue under the barrier wait
    const unsigned short* pwq = wq + 49152;
    frag8 wf2[2][4];
#pragma unroll
    for (int ct = 0; ct < 2; ++ct)
#pragma unroll
        for (int ks = 0; ks < 4; ++ks)
            wf2[ct][ks] = *(const frag8*)(pwq + (size_t)(h * 32 + ct * 16 + n16) * C_DIM + ks * 32 + q * 8);
    float4 pb4[2];
#pragma unroll
    for (int ct = 0; ct < 2; ++ct)
        pb4[ct] = *(const float4*)(proj_b + h * 32 + ct * 16 + q * 4);
    __syncthreads();  // (4) act complete

    // ---- Phase D: out^T = W act^T -> float4 stores ----
    float* outb = out + (size_t)b * 6272;
    frag8 af[4][4];
#pragma unroll
    for (int nt = 0; nt < 4; ++nt)
#pragma unroll
        for (int ks = 0; ks < 4; ++ks)
            af[nt][ks] = *(const frag8*)&sm[min(nt * 16 + n16, 48) * XACT_STR + ks * 32 + q * 8];
#pragma unroll
    for (int nt = 0; nt < 4; ++nt) {
        int tok = nt * 16 + n16;
#pragma unroll
        for (int ct = 0; ct < 2; ++ct) {
            f32x4 acc = {0.f, 0.f, 0.f, 0.f};
#pragma unroll
            for (int ks = 0; ks < 4; ++ks)
                acc = __builtin_amdgcn_mfma_f32_16x16x32_bf16(wf2[ct][ks], af[nt][ks], acc, 0, 0, 0);
            if (tok < 49)
                *(float4*)&outb[tok * C_DIM + h * 32 + ct * 16 + q * 4] =
                    make_float4(acc[0] + pb4[ct].x, acc[1] + pb4[ct].y,
                                acc[2] + pb4[ct].z, acc[3] + pb4[ct].w);
        }
    }
}

extern "C" void kernel_launch(void* const* d_in, const int* in_sizes, int n_in,
                              void* d_out, int out_size, void* d_ws, size_t ws_size,
                              hipStream_t stream) {
    const float* x      = (const float*)d_in[0];
    const float* mask   = (const float*)d_in[1];
    const float* qkv_b  = (const float*)d_in[3];
    const float* proj_b = (const float*)d_in[5];

    unsigned short* wbf = (unsigned short*)d_ws;                   // 131072 B
    float* pmask = (float*)((char*)d_ws + 131072);                 // 802816 B
    convert_weights<<<64, 256, 0, stream>>>((const float4*)d_in[2],
                                            (const float4*)d_in[4],
                                            (ushort4*)wbf);
    pad_mask<<<196, 256, 0, stream>>>(mask, pmask);
    attn_mfma<<<4096, 256, 0, stream>>>(x, pmask, qkv_b, proj_b, wbf, (float*)d_out);
}

// Round 5
// 270.003 us; speedup vs baseline: 1.2099x; 1.0259x over previous
//
#include <hip/hip_runtime.h>
#include <hip/hip_bf16.h>

#define C_DIM 128
#define SCALE 0.17677669529663687f

typedef __attribute__((ext_vector_type(8))) short frag8;
typedef __attribute__((ext_vector_type(4))) float f32x4;
typedef __attribute__((ext_vector_type(4))) unsigned int u32x4;

// ---- LDS (ushort units), 17216 total = 34432 B -> 4 blocks/CU ----
//  [0,8000)      K block: head h at h*2000, rows 50 x Q_STR=40 (row 49 trash)
//  [8000,17216)  Vt block: head h at 8000+h*2304, rows 32 x VT_STR=72
//                (token cols 49..63 garbage, cancelled by P zeros)
//  x staging rows 0..48 stride 136 = [0,6664) overlays K block (dead after
//  barrier 2); act rows 0..49 stride 136 = [0,6800) overlays K block (safe
//  after barrier 3 = all kf reads retired).
// Q and P live ONLY in registers: the C-layout -> A/B-frag conversion is a
// cross-q-group shuffle (srcA=((q&1)<<5)+n16, srcB=srcA+16, tile sel = q>>1).
// Pad tokens: reads clamp row to 48; writes go to trash row 49; softmax guards
// j<49 (garbage keys, incl. cross-head race garbage, only feed masked cols).
//
// LAUNCH BOUNDS HISTORY (do not regress):
//  (256,4): allocator squeezed to 64 VGPR to hit the 8-waves/EU bucket ->
//           massive scratch spill (WRITE_SIZE 3x), 199us.  [round 3]
//  (256,3): no spill (VGPR 68) but residency pinned at 3 blocks/CU (30% occ)
//           even though LDS allows 4.                      [round 4]
//  (256):   no waves-per-eu metadata -> natural VGPR, LDS-limited residency
//           (4 blocks/CU expected).                        [this round]
#define XACT_STR 136
#define VT_BASE 8000
#define VT_PER_HEAD 2304
#define Q_STR 40
#define VT_STR 72
#define SMEM_TOT 17216

__device__ __forceinline__ unsigned short f2b(float x) {
    __hip_bfloat16 h = __float2bfloat16(x);
    return __builtin_bit_cast(unsigned short, h);
}
__device__ __forceinline__ unsigned pk2(float a, float b) {
    return ((unsigned)f2b(b) << 16) | (unsigned)f2b(a);
}
__device__ __forceinline__ void add4(f32x4& a, float4 m) {
    a[0] += m.x; a[1] += m.y; a[2] += m.z; a[3] += m.w;
}

// fp32 weights -> bf16 ws: [0,49152) qkv_w, [49152,65536) proj_w
__global__ void convert_weights(const float4* __restrict__ qkvw,
                                const float4* __restrict__ projw,
                                ushort4* __restrict__ wbf) {
    int i = blockIdx.x * 256 + threadIdx.x;
    float4 v = (i < 12288) ? qkvw[i] : projw[i - 12288];
    ushort4 p;
    p.x = f2b(v.x); p.y = f2b(v.y); p.z = f2b(v.z); p.w = f2b(v.w);
    wbf[i] = p;
}

// mask[64][49][49] fp32 -> pm[64][49][64] fp32 (cols 49..63 = 0).
__global__ void pad_mask(const float* __restrict__ mask, float* __restrict__ pm) {
    int t = blockIdx.x * 256 + threadIdx.x;      // 196*256 = 50176 exactly
    int w = t / 784, rem = t % 784, i = rem >> 4, tq = rem & 15;
    const float* src = mask + (size_t)w * 2401 + i * 49;
    int j = tq * 4;
    float4 v;
    v.x = (j     < 49) ? src[j]     : 0.f;
    v.y = (j + 1 < 49) ? src[j + 1] : 0.f;
    v.z = (j + 2 < 49) ? src[j + 2] : 0.f;
    v.w = (j + 3 < 49) ? src[j + 3] : 0.f;
    ((float4*)pm)[t] = v;
}

__global__ __launch_bounds__(256) void attn_mfma(
    const float* __restrict__ x,
    const float* __restrict__ pmask,
    const float* __restrict__ qkv_b,
    const float* __restrict__ proj_b,
    const unsigned short* __restrict__ wq,
    float* __restrict__ out)
{
    __shared__ __align__(16) unsigned short sm[SMEM_TOT];

    const int b = blockIdx.x, tid = threadIdx.x;
    const int h    = tid >> 6;   // wave = head, owns the full chain
    const int lane = tid & 63;
    const int n16  = lane & 15;
    const int q    = lane >> 4;

    // ---- stage x[b] rows 0..48 -> bf16 (base 0, stride 136) ----
    {
        const float4* xg = (const float4*)(x + (size_t)b * 6272);
        for (int i = tid; i < 1568; i += 256) {
            float4 v = xg[i];
            int row = i >> 5, col = (i & 31) << 2;
            uint2 pk; pk.x = pk2(v.x, v.y); pk.y = pk2(v.z, v.w);
            *(uint2*)&sm[row * XACT_STR + col] = pk;
        }
    }
    __syncthreads();  // (1) x staged

    // ---- x frags, pad rows clamp to row 48 ----
    frag8 xf[4][4];
#pragma unroll
    for (int tt = 0; tt < 4; ++tt)
#pragma unroll
        for (int ks = 0; ks < 4; ++ks)
            xf[tt][ks] = *(const frag8*)&sm[min(tt * 16 + n16, 48) * XACT_STR + ks * 32 + q * 8];
    __syncthreads();  // (2) x in regs everywhere -> K/Vt writes may overlay staging

    const int KB = h * 2000;
    const int VB = VT_BASE + h * VT_PER_HEAD;

    // ---- Phase A: K first (max LDS write->read gap), then V, then Q ----
    // K: D = W x^T -> K[tok][ch] in LDS
#pragma unroll
    for (int ct = 0; ct < 2; ++ct) {
        const unsigned short* wrow = wq + (size_t)(C_DIM + h * 32 + ct * 16 + n16) * C_DIM;
        frag8 wf[4];
#pragma unroll
        for (int ks = 0; ks < 4; ++ks) wf[ks] = *(const frag8*)(wrow + ks * 32 + q * 8);
        float4 b4 = *(const float4*)(qkv_b + C_DIM + h * 32 + ct * 16 + q * 4);
#pragma unroll
        for (int tt = 0; tt < 4; ++tt) {
            f32x4 acc = {0.f, 0.f, 0.f, 0.f};
#pragma unroll
            for (int ks = 0; ks < 4; ++ks)
                acc = __builtin_amdgcn_mfma_f32_16x16x32_bf16(wf[ks], xf[tt][ks], acc, 0, 0, 0);
            uint2 pk;
            pk.x = pk2(acc[0] + b4.x, acc[1] + b4.y);
            pk.y = pk2(acc[2] + b4.z, acc[3] + b4.w);
            *(uint2*)&sm[KB + min(tt * 16 + n16, 49) * Q_STR + ct * 16 + q * 4] = pk;
        }
    }
    // V: D = x W^T -> Vt[ch][tok] in LDS
#pragma unroll
    for (int ct = 0; ct < 2; ++ct) {
        const unsigned short* wrow = wq + (size_t)(2 * C_DIM + h * 32 + ct * 16 + n16) * C_DIM;
        frag8 wf[4];
#pragma unroll
        for (int ks = 0; ks < 4; ++ks) wf[ks] = *(const frag8*)(wrow + ks * 32 + q * 8);
        float bias = qkv_b[2 * C_DIM + h * 32 + ct * 16 + n16];
#pragma unroll
        for (int tt = 0; tt < 4; ++tt) {
            f32x4 acc = {0.f, 0.f, 0.f, 0.f};
#pragma unroll
            for (int ks = 0; ks < 4; ++ks)
                acc = __builtin_amdgcn_mfma_f32_16x16x32_bf16(xf[tt][ks], wf[ks], acc, 0, 0, 0);
            uint2 pk;
            pk.x = pk2(acc[0] + bias, acc[1] + bias);
            pk.y = pk2(acc[2] + bias, acc[3] + bias);
            *(uint2*)&sm[VB + (ct * 16 + n16) * VT_STR + tt * 16 + q * 4] = pk;
        }
    }
    // Q: D = W x^T kept as packed bf16 words in regs (qw[tt][ct][w]),
    // word w = ch pair (ct*16+q*4+2w, +2w+1) for tok tt*16+n16.
    unsigned qw[4][2][2];
#pragma unroll
    for (int ct = 0; ct < 2; ++ct) {
        const unsigned short* wrow = wq + (size_t)(h * 32 + ct * 16 + n16) * C_DIM;
        frag8 wf[4];
#pragma unroll
        for (int ks = 0; ks < 4; ++ks) wf[ks] = *(const frag8*)(wrow + ks * 32 + q * 8);
        float4 b4 = *(const float4*)(qkv_b + h * 32 + ct * 16 + q * 4);
#pragma unroll
        for (int tt = 0; tt < 4; ++tt) {
            f32x4 acc = {0.f, 0.f, 0.f, 0.f};
#pragma unroll
            for (int ks = 0; ks < 4; ++ks)
                acc = __builtin_amdgcn_mfma_f32_16x16x32_bf16(wf[ks], xf[tt][ks], acc, 0, 0, 0);
            qw[tt][ct][0] = pk2((acc[0] + b4.x) * SCALE, (acc[1] + b4.y) * SCALE);
            qw[tt][ct][1] = pk2((acc[2] + b4.z) * SCALE, (acc[3] + b4.w) * SCALE);
        }
    }

    // ---- qf via register shuffles (no LDS round trip) ----
    // qf[it] elem e = Q[tok=it*16+n16][ch=q*8+e]: src lane ((q&1)<<5)+n16
    // (+16 for e>=4), word = (e&3)>>1, ct sel = q>>1.
    const int srcA = ((q & 1) << 5) + n16;
    const int srcB = srcA + 16;
    const int hi = q >> 1;
    frag8 qf[4];
#pragma unroll
    for (int it = 0; it < 4; ++it) {
        unsigned a00 = __shfl((int)qw[it][0][0], srcA);
        unsigned a10 = __shfl((int)qw[it][1][0], srcA);
        unsigned a01 = __shfl((int)qw[it][0][1], srcA);
        unsigned a11 = __shfl((int)qw[it][1][1], srcA);
        unsigned b00 = __shfl((int)qw[it][0][0], srcB);
        unsigned b10 = __shfl((int)qw[it][1][0], srcB);
        unsigned b01 = __shfl((int)qw[it][0][1], srcB);
        unsigned b11 = __shfl((int)qw[it][1][1], srcB);
        u32x4 t;
        t[0] = hi ? a10 : a00;
        t[1] = hi ? a11 : a01;
        t[2] = hi ? b10 : b00;
        t[3] = hi ? b11 : b01;
        qf[it] = __builtin_bit_cast(frag8, t);
    }

    // ---- kf/vf loads (kf rows 49..63 garbage -> masked cols; race-safe) ----
    frag8 kf[4];
#pragma unroll
    for (int t = 0; t < 4; ++t)
        kf[t] = *(const frag8*)&sm[KB + (t * 16 + n16) * Q_STR + q * 8];
    frag8 vf[2][2];
#pragma unroll
    for (int ct = 0; ct < 2; ++ct)
#pragma unroll
        for (int ks = 0; ks < 2; ++ks)
            vf[ct][ks] = *(const frag8*)&sm[VB + (ct * 16 + n16) * VT_STR + ks * 32 + q * 8];
    __syncthreads();  // (3) all kf reads retired -> act may overlay K block

    // ---- fused S -> softmax -> PV per 16-query tile ----
    const float4* pm4 = (const float4*)(pmask + (size_t)(b & 63) * 3136);
    f32x4 o[2][4];
#pragma unroll
    for (int ct = 0; ct < 2; ++ct)
#pragma unroll
        for (int nt = 0; nt < 4; ++nt) o[ct][nt] = (f32x4){0.f, 0.f, 0.f, 0.f};

#pragma unroll
    for (int it = 0; it < 4; ++it) {
        int ii = min(it * 16 + n16, 48);
        float4 mj[4];
#pragma unroll
        for (int jt = 0; jt < 4; ++jt) mj[jt] = pm4[ii * 16 + q + jt * 4];

        f32x4 s4[4];
#pragma unroll
        for (int jt = 0; jt < 4; ++jt) {
            s4[jt] = (f32x4){0.f, 0.f, 0.f, 0.f};
            s4[jt] = __builtin_amdgcn_mfma_f32_16x16x32_bf16(kf[jt], qf[it], s4[jt], 0, 0, 0);
        }
#pragma unroll
        for (int jt = 0; jt < 4; ++jt) add4(s4[jt], mj[jt]);

        float mx = -1e30f;
#pragma unroll
        for (int jt = 0; jt < 4; ++jt)
#pragma unroll
            for (int r = 0; r < 4; ++r)
                if (jt * 16 + q * 4 + r < 49) mx = fmaxf(mx, s4[jt][r]);
        mx = fmaxf(mx, __shfl_xor(mx, 16));
        mx = fmaxf(mx, __shfl_xor(mx, 32));

        float sum = 0.f;
#pragma unroll
        for (int jt = 0; jt < 4; ++jt)
#pragma unroll
            for (int r = 0; r < 4; ++r) {
                float e = (jt * 16 + q * 4 + r < 49) ? __expf(s4[jt][r] - mx) : 0.f;
                s4[jt][r] = e;
                sum += e;
            }
        sum += __shfl_xor(sum, 16);
        sum += __shfl_xor(sum, 32);
        float inv = __builtin_amdgcn_rcpf(sum);

        // pack unnormalized P (e in (0,1], bf16-safe); normalize o afterwards
        unsigned pw[4][2];
#pragma unroll
        for (int jt = 0; jt < 4; ++jt) {
            pw[jt][0] = pk2(s4[jt][0], s4[jt][1]);
            pw[jt][1] = pk2(s4[jt][2], s4[jt][3]);
        }
        // pf[ks] elem e = P[key=ks*32+q*8+e][tok=it*16+n16]: jt sel = 2ks+hi
#pragma unroll
        for (int ks = 0; ks < 2; ++ks) {
            unsigned a0  = __shfl((int)pw[2 * ks][0],     srcA);
            unsigned a0h = __shfl((int)pw[2 * ks + 1][0], srcA);
            unsigned a1  = __shfl((int)pw[2 * ks][1],     srcA);
            unsigned a1h = __shfl((int)pw[2 * ks + 1][1], srcA);
            unsigned b0  = __shfl((int)pw[2 * ks][0],     srcB);
            unsigned b0h = __shfl((int)pw[2 * ks + 1][0], srcB);
            unsigned b1  = __shfl((int)pw[2 * ks][1],     srcB);
            unsigned b1h = __shfl((int)pw[2 * ks + 1][1], srcB);
            u32x4 t;
            t[0] = hi ? a0h : a0;
            t[1] = hi ? a1h : a1;
            t[2] = hi ? b0h : b0;
            t[3] = hi ? b1h : b1;
            frag8 pf = __builtin_bit_cast(frag8, t);
#pragma unroll
            for (int ct = 0; ct < 2; ++ct)
                o[ct][it] = __builtin_amdgcn_mfma_f32_16x16x32_bf16(vf[ct][ks], pf, o[ct][it], 0, 0, 0);
        }
#pragma unroll
        for (int ct = 0; ct < 2; ++ct)
#pragma unroll
            for (int r = 0; r < 4; ++r) o[ct][it][r] *= inv;
    }

    // ---- act[tok][128ch] rows 0..49 stride 136 overlays K block ----
#pragma unroll
    for (int ct = 0; ct < 2; ++ct)
#pragma unroll
        for (int nt = 0; nt < 4; ++nt) {
            uint2 pk;
            pk.x = pk2(o[ct][nt][0], o[ct][nt][1]);
            pk.y = pk2(o[ct][nt][2], o[ct][nt][3]);
            *(uint2*)&sm[min(nt * 16 + n16, 49) * XACT_STR + h * 32 + ct * 16 + q * 4] = pk;
        }

    // proj weights + biases: issue under the barrier wait
    const unsigned short* pwq = wq + 49152;
    frag8 wf2[2][4];
#pragma unroll
    for (int ct = 0; ct < 2; ++ct)
#pragma unroll
        for (int ks = 0; ks < 4; ++ks)
            wf2[ct][ks] = *(const frag8*)(pwq + (size_t)(h * 32 + ct * 16 + n16) * C_DIM + ks * 32 + q * 8);
    float4 pb4[2];
#pragma unroll
    for (int ct = 0; ct < 2; ++ct)
        pb4[ct] = *(const float4*)(proj_b + h * 32 + ct * 16 + q * 4);
    __syncthreads();  // (4) act complete

    // ---- Phase D: out^T = W act^T -> float4 stores ----
    float* outb = out + (size_t)b * 6272;
    frag8 af[4][4];
#pragma unroll
    for (int nt = 0; nt < 4; ++nt)
#pragma unroll
        for (int ks = 0; ks < 4; ++ks)
            af[nt][ks] = *(const frag8*)&sm[min(nt * 16 + n16, 48) * XACT_STR + ks * 32 + q * 8];
#pragma unroll
    for (int nt = 0; nt < 4; ++nt) {
        int tok = nt * 16 + n16;
#pragma unroll
        for (int ct = 0; ct < 2; ++ct) {
            f32x4 acc = {0.f, 0.f, 0.f, 0.f};
#pragma unroll
            for (int ks = 0; ks < 4; ++ks)
                acc = __builtin_amdgcn_mfma_f32_16x16x32_bf16(wf2[ct][ks], af[nt][ks], acc, 0, 0, 0);
            if (tok < 49)
                *(float4*)&outb[tok * C_DIM + h * 32 + ct * 16 + q * 4] =
                    make_float4(acc[0] + pb4[ct].x, acc[1] + pb4[ct].y,
                                acc[2] + pb4[ct].z, acc[3] + pb4[ct].w);
        }
    }
}

extern "C" void kernel_launch(void* const* d_in, const int* in_sizes, int n_in,
                              void* d_out, int out_size, void* d_ws, size_t ws_size,
                              hipStream_t stream) {
    const float* x      = (const float*)d_in[0];
    const float* mask   = (const float*)d_in[1];
    const float* qkv_b  = (const float*)d_in[3];
    const float* proj_b = (const float*)d_in[5];

    unsigned short* wbf = (unsigned short*)d_ws;                   // 131072 B
    float* pmask = (float*)((char*)d_ws + 131072);                 // 802816 B
    convert_weights<<<64, 256, 0, stream>>>((const float4*)d_in[2],
                                            (const float4*)d_in[4],
                                            (ushort4*)wbf);
    pad_mask<<<196, 256, 0, stream>>>(mask, pmask);
    attn_mfma<<<4096, 256, 0, stream>>>(x, pmask, qkv_b, proj_b, wbf, (float*)d_out);
}